// Round 2
// baseline (1131.307 us; speedup 1.0000x reference)
//
#include <hip/hip_runtime.h>
#include <math.h>

// N=100000 nodes, E=1600000 edges, F_IN=10 (+2 idx cols), H=128, G=1000 graphs, GAP=3
#define H 128
#define GAPLEN 3
#define DIN 18   // 10 float feats + 4 ship emb + 4 nav emb

static inline int ceil_div(int a, int b){ return (a + b - 1) / b; }

// ---------------- feats = [x[:, :10], ship_emb[x[:,10]], nav_emb[x[:,11]]] ----------------
__global__ void build_feats_k(const float* __restrict__ x, const float* __restrict__ se,
                              const float* __restrict__ ne, float* __restrict__ f, int n){
  int i = blockIdx.x * 256 + threadIdx.x;
  if (i >= n) return;
  const float* xr = x + (size_t)i * 12;
  float* fr = f + (size_t)i * DIN;
#pragma unroll
  for (int c = 0; c < 10; ++c) fr[c] = xr[c];
  int st = (int)xr[10];
  int nv = (int)xr[11];
#pragma unroll
  for (int c = 0; c < 4; ++c){
    fr[10 + c] = se[st * 4 + c];
    fr[14 + c] = ne[nv * 4 + c];
  }
}

// =================== bucketed CSR build ===================
// buckets of 128 dst nodes. Pipeline:
//  A) coarse histogram over buckets (LDS-staged)
//  B) exclusive scan of bucket counts -> bbase
//  C) partition edges into buckets (packed (dstlocal<<17)|src), clustered appends
//  D) per-bucket: node histogram, scan -> rp/cnt/dis, scatter src into csr

#define CHUNK 4096   // edges per block in passes A/C (256 thr x 16)

__global__ __launch_bounds__(256) void bhistA_k(const int* __restrict__ ei, int* __restrict__ bh,
                                                int E, int NB){
  __shared__ int lh[1024];
  int t = threadIdx.x;
  for (int j = t; j < 1024; j += 256) lh[j] = 0;
  __syncthreads();
  int base = blockIdx.x * CHUNK;
#pragma unroll
  for (int i = 0; i < 16; ++i){
    int e = base + i * 256 + t;
    if (e < E) atomicAdd(&lh[ei[E + e] >> 7], 1);
  }
  __syncthreads();
  for (int j = t; j < NB; j += 256){
    int v = lh[j];
    if (v) atomicAdd(&bh[j], v);
  }
}

__global__ void bscan_k(const int* __restrict__ bh, int* __restrict__ bbase, int NB){
  __shared__ int sd[1024];
  int t = threadIdx.x;
  int v = (t < NB) ? bh[t] : 0;
  sd[t] = v;
  __syncthreads();
  for (int off = 1; off < 1024; off <<= 1){
    int add = (t >= off) ? sd[t - off] : 0;
    __syncthreads();
    sd[t] += add;
    __syncthreads();
  }
  if (t < NB) bbase[t] = sd[t] - v;
}

__global__ __launch_bounds__(256) void bpartC_k(const int* __restrict__ ei,
                                                const int* __restrict__ bbase,
                                                int* __restrict__ bcur,
                                                int* __restrict__ ebuf, int E, int NB){
  __shared__ int lh[1024];     // per-block bucket counts
  __shared__ int lchunk[1024]; // global chunk base for this block
  __shared__ int lcur[1024];   // within-chunk cursor
  int t = threadIdx.x;
  for (int j = t; j < 1024; j += 256) lh[j] = 0;
  __syncthreads();
  int base = blockIdx.x * CHUNK;
  int pk[16], bk[16];
#pragma unroll
  for (int i = 0; i < 16; ++i){
    int e = base + i * 256 + t;
    if (e < E){
      int s = ei[e];
      int d = ei[E + e];
      bk[i] = d >> 7;
      pk[i] = ((d & 127) << 17) | s;
      atomicAdd(&lh[bk[i]], 1);
    } else bk[i] = -1;
  }
  __syncthreads();
  for (int j = t; j < NB; j += 256){
    int c = lh[j];
    if (c) lchunk[j] = bbase[j] + atomicAdd(&bcur[j], c);
    lcur[j] = 0;
  }
  __syncthreads();
#pragma unroll
  for (int i = 0; i < 16; ++i){
    if (bk[i] >= 0){
      int off = atomicAdd(&lcur[bk[i]], 1);
      ebuf[lchunk[bk[i]] + off] = pk[i];
    }
  }
}

__global__ __launch_bounds__(256) void bbuildD_k(const int* __restrict__ ebuf,
                                                 const int* __restrict__ bh,
                                                 const int* __restrict__ bbase,
                                                 int* __restrict__ rp, int* __restrict__ cnt,
                                                 float* __restrict__ dis, int* __restrict__ csr,
                                                 int n){
  __shared__ int hist[128], sc[128], gb[128], curr[128];
  int b = blockIdx.x;
  int t = threadIdx.x;
  int sb = bbase[b];
  int mb = bh[b];
  if (t < 128) hist[t] = 0;
  __syncthreads();
  for (int i = t; i < mb; i += 256)
    atomicAdd(&hist[ebuf[sb + i] >> 17], 1);
  __syncthreads();
  if (t < 128) sc[t] = hist[t];
  __syncthreads();
  for (int off = 1; off < 128; off <<= 1){
    int add = (t < 128 && t >= off) ? sc[t - off] : 0;
    __syncthreads();
    if (t < 128) sc[t] += add;
    __syncthreads();
  }
  if (t < 128){
    int node = b * 128 + t;
    int rpv = sb + sc[t] - hist[t];  // exclusive
    gb[t] = rpv;
    curr[t] = 0;
    if (node < n){
      rp[node] = rpv;
      cnt[node] = hist[t];
      dis[node] = rsqrtf((float)hist[t] + 1.0f);
    }
  }
  __syncthreads();
  for (int i = t; i < mb; i += 256){
    int p = ebuf[sb + i];
    int dl = p >> 17;
    int src = p & 0x1FFFF;
    int off = atomicAdd(&curr[dl], 1);
    csr[gb[dl] + off] = src;
  }
}

// ---------------- aggregation, d=18 (layer 1 input) ----------------
__global__ void agg18_k(const float* __restrict__ f, const float* __restrict__ dis,
                        const int* __restrict__ rp, const int* __restrict__ cnt,
                        const int* __restrict__ csr, float* __restrict__ out, int n){
  int node = blockIdx.x * 8 + (threadIdx.x >> 5);
  if (node >= n) return;
  int lane = threadIdx.x & 31;
  bool act = lane < DIN;
  int start = rp[node];
  int m = cnt[node];
  float acc = 0.f;
  for (int e = 0; e < m; ++e){
    int s = csr[start + e];
    float w = dis[s];
    if (act) acc += w * f[(size_t)s * DIN + lane];
  }
  float di = dis[node];
  if (act){
    float self = f[(size_t)node * DIN + lane];
    out[(size_t)node * DIN + lane] = di * (acc + di * self);
  }
}

// ---------------- aggregation, d=128, feature-sliced for XCD L2 affinity ----------------
// slice = blockIdx.x & 7  (round-robin XCD dispatch -> slice s lands on XCD s)
// each XCD's h working set: 16 cols x 100K nodes x 4B = 6.4 MB (~L2 sized)
__global__ __launch_bounds__(256) void agg128s_k(const float* __restrict__ h,
                                                 const float* __restrict__ dis,
                                                 const int* __restrict__ rp,
                                                 const int* __restrict__ cnt,
                                                 const int* __restrict__ csr,
                                                 float* __restrict__ out, int n){
  int bid = blockIdx.x;
  int slice = bid & 7;
  int tile = bid >> 3;
  int g = threadIdx.x >> 4;     // 16 node-groups per block
  int lane = threadIdx.x & 15;  // 16 cols per slice
  int node = tile * 16 + g;
  if (node >= n) return;
  int c = slice * 16 + lane;
  int start = rp[node];
  int m = cnt[node];
  float acc = 0.f;
  int e = 0;
  for (; e + 1 < m; e += 2){
    int s0 = csr[start + e];
    int s1 = csr[start + e + 1];
    float w0 = dis[s0];
    float w1 = dis[s1];
    acc += w0 * h[(size_t)s0 * H + c] + w1 * h[(size_t)s1 * H + c];
  }
  if (e < m){
    int s = csr[start + e];
    acc += dis[s] * h[(size_t)s * H + c];
  }
  float di = dis[node];
  out[(size_t)node * H + c] = di * (acc + di * h[(size_t)node * H + c]);
}

// ---------------- GEMM: [n,18] @ [18,128] + bias, relu ----------------
__global__ void gemm18_k(const float* __restrict__ A, const float* __restrict__ W,
                         const float* __restrict__ b, float* __restrict__ C, int n){
  __shared__ float sw[DIN * H];
  __shared__ float sb[H];
  __shared__ float sa[8][DIN];
  int t = threadIdx.x;
  for (int i = t; i < DIN * H; i += 256) sw[i] = W[i];
  if (t < H) sb[t] = b[t];
  int row0 = blockIdx.x * 8;
  for (int i = t; i < 8 * DIN; i += 256){
    int r = i / DIN, c = i % DIN;
    int rr = row0 + r;
    sa[r][c] = (rr < n) ? A[(size_t)rr * DIN + c] : 0.f;
  }
  __syncthreads();
  int r = t >> 5, lane = t & 31;
  int row = row0 + r;
  if (row >= n) return;
  int c0 = lane * 4;
  float ox = sb[c0], oy = sb[c0 + 1], oz = sb[c0 + 2], ow = sb[c0 + 3];
#pragma unroll
  for (int k = 0; k < DIN; ++k){
    float a = sa[r][k];
    const float4 w = *(const float4*)&sw[k * H + c0];
    ox += a * w.x; oy += a * w.y; oz += a * w.z; ow += a * w.w;
  }
  float4 o;
  o.x = fmaxf(ox, 0.f); o.y = fmaxf(oy, 0.f); o.z = fmaxf(oz, 0.f); o.w = fmaxf(ow, 0.f);
  *(float4*)&C[(size_t)row * H + c0] = o;
}

// ---------------- GEMM: [n,128] @ [128,128] + bias, relu ----------------
__global__ __launch_bounds__(128) void gemm128_k(const float* __restrict__ A,
                                                 const float* __restrict__ B,
                                                 const float* __restrict__ bias,
                                                 float* __restrict__ C, int n){
  __shared__ float sa[32][64];  // [k][row]
  int t = threadIdx.x;
  int row0 = blockIdx.x * 64;
  int tc = t & 15;
  int tr = t >> 4;
  float acc[8][8];
#pragma unroll
  for (int i = 0; i < 8; ++i)
#pragma unroll
    for (int j = 0; j < 8; ++j) acc[i][j] = 0.f;

  int lr = t >> 1;
  int lc = (t & 1) * 16;
  for (int k0 = 0; k0 < H; k0 += 32){
    const float* Ar = A + (size_t)(row0 + lr) * H + k0 + lc;
    bool rowok = (row0 + lr) < n;
    float4 v0, v1, v2, v3;
    if (rowok){
      v0 = *(const float4*)(Ar + 0);
      v1 = *(const float4*)(Ar + 4);
      v2 = *(const float4*)(Ar + 8);
      v3 = *(const float4*)(Ar + 12);
    } else {
      v0 = v1 = v2 = v3 = float4{0.f, 0.f, 0.f, 0.f};
    }
    __syncthreads();
    float vv[16] = {v0.x, v0.y, v0.z, v0.w, v1.x, v1.y, v1.z, v1.w,
                    v2.x, v2.y, v2.z, v2.w, v3.x, v3.y, v3.z, v3.w};
#pragma unroll
    for (int i = 0; i < 16; ++i) sa[lc + i][lr] = vv[i];
    __syncthreads();

    const float* Bp = B + (size_t)k0 * H + tc * 8;
#pragma unroll
    for (int k = 0; k < 32; ++k){
      float4 b0 = *(const float4*)(Bp + (size_t)k * H);
      float4 b1 = *(const float4*)(Bp + (size_t)k * H + 4);
      float4 a0 = *(const float4*)&sa[k][tr * 8];
      float4 a1 = *(const float4*)&sa[k][tr * 8 + 4];
      float aa[8] = {a0.x, a0.y, a0.z, a0.w, a1.x, a1.y, a1.z, a1.w};
      float bb[8] = {b0.x, b0.y, b0.z, b0.w, b1.x, b1.y, b1.z, b1.w};
#pragma unroll
      for (int i = 0; i < 8; ++i)
#pragma unroll
        for (int j = 0; j < 8; ++j) acc[i][j] += aa[i] * bb[j];
    }
  }
  float bb[8];
#pragma unroll
  for (int j = 0; j < 8; ++j) bb[j] = bias[tc * 8 + j];
#pragma unroll
  for (int i = 0; i < 8; ++i){
    int row = row0 + tr * 8 + i;
    if (row < n){
      float4 o0, o1;
      o0.x = fmaxf(acc[i][0] + bb[0], 0.f);
      o0.y = fmaxf(acc[i][1] + bb[1], 0.f);
      o0.z = fmaxf(acc[i][2] + bb[2], 0.f);
      o0.w = fmaxf(acc[i][3] + bb[3], 0.f);
      o1.x = fmaxf(acc[i][4] + bb[4], 0.f);
      o1.y = fmaxf(acc[i][5] + bb[5], 0.f);
      o1.z = fmaxf(acc[i][6] + bb[6], 0.f);
      o1.w = fmaxf(acc[i][7] + bb[7], 0.f);
      float* Cp = C + (size_t)row * H + tc * 8;
      *(float4*)(Cp) = o0;
      *(float4*)(Cp + 4) = o1;
    }
  }
}

// ---------------- graph counts histogram + scan + gap gather ----------------
__global__ void ghist_k(const int* __restrict__ batch, int* __restrict__ gc, int n){
  int i = blockIdx.x * 256 + threadIdx.x;
  if (i < n) atomicAdd(&gc[batch[i]], 1);
}

__global__ void gscan_k(const int* __restrict__ gc, int* __restrict__ go, int G){
  __shared__ int sd[1024];
  int t = threadIdx.x;
  int v = (t < G) ? gc[t] : 0;
  sd[t] = v;
  __syncthreads();
  for (int off = 1; off < 1024; off <<= 1){
    int add = (t >= off) ? sd[t - off] : 0;
    __syncthreads();
    sd[t] += add;
    __syncthreads();
  }
  if (t < G) go[t] = sd[t] - v;
}

__global__ void gather_k(const float* __restrict__ h, const int* __restrict__ go,
                         const int* __restrict__ gap, float* __restrict__ inp,
                         float* __restrict__ hf, float* __restrict__ hb, int G){
  int g = blockIdx.x;
  int t = threadIdx.x;
  if (g >= G) return;
  int idx = go[g] + gap[0];
  float v = h[(size_t)idx * H + t];
  inp[(size_t)g * H + t] = v;
  hf[(size_t)g * H + t] = v;
  hb[(size_t)g * H + t] = v;
}

// ---------------- GRU step ----------------
__global__ __launch_bounds__(256) void gru_k(const float* __restrict__ inp,
                                             float* __restrict__ hf, float* __restrict__ hb,
                                             const float* __restrict__ Wih_f, const float* __restrict__ Whh_f,
                                             const float* __restrict__ bih_f, const float* __restrict__ bhh_f,
                                             const float* __restrict__ Wih_b, const float* __restrict__ Whh_b,
                                             const float* __restrict__ bih_b, const float* __restrict__ bhh_b,
                                             int G){
  int cell = blockIdx.y;
  const float* Wih = cell ? Wih_b : Wih_f;
  const float* Whh = cell ? Whh_b : Whh_f;
  const float* bih = cell ? bih_b : bih_f;
  const float* bhh = cell ? bhh_b : bhh_f;
  float* h = cell ? hb : hf;

  __shared__ float sx[16][H];
  __shared__ float sh[16][H];
  int g0 = blockIdx.x * 16;
  int t = threadIdx.x;
  for (int i = t; i < 16 * H; i += 256){
    int g = i >> 7, c = i & 127;
    int gg = g0 + g;
    sx[g][c] = (gg < G) ? inp[(size_t)gg * H + c] : 0.f;
    sh[g][c] = (gg < G) ? h[(size_t)gg * H + c] : 0.f;
  }
  __syncthreads();
  int j = t & 127;
  int gs = (t >> 7) * 8;
  float ar[8] = {0}, az[8] = {0}, an[8] = {0};
  float br[8] = {0}, bz[8] = {0}, bn[8] = {0};
  for (int k = 0; k < H; ++k){
    float wr = Wih[k * 384 + j];
    float wz = Wih[k * 384 + 128 + j];
    float wn = Wih[k * 384 + 256 + j];
    float ur = Whh[k * 384 + j];
    float uz = Whh[k * 384 + 128 + j];
    float un = Whh[k * 384 + 256 + j];
#pragma unroll
    for (int g = 0; g < 8; ++g){
      float xv = sx[gs + g][k];
      float hv = sh[gs + g][k];
      ar[g] += xv * wr; az[g] += xv * wz; an[g] += xv * wn;
      br[g] += hv * ur; bz[g] += hv * uz; bn[g] += hv * un;
    }
  }
  float bir = bih[j], biz = bih[128 + j], bin = bih[256 + j];
  float bhr = bhh[j], bhz = bhh[128 + j], bhn = bhh[256 + j];
#pragma unroll
  for (int g = 0; g < 8; ++g){
    int gg = g0 + gs + g;
    if (gg < G){
      float r = 1.f / (1.f + expf(-(ar[g] + bir + br[g] + bhr)));
      float z = 1.f / (1.f + expf(-(az[g] + biz + bz[g] + bhz)));
      float nn = tanhf(an[g] + bin + r * (bn[g] + bhn));
      float hv = sh[gs + g][j];
      h[(size_t)gg * H + j] = (1.f - z) * nn + z * hv;
    }
  }
}

// ---------------- post step ----------------
__global__ __launch_bounds__(256) void post_k(const float* __restrict__ hf, const float* __restrict__ hb,
                                              const float* __restrict__ Wred, const float* __restrict__ bred,
                                              const float* __restrict__ Wh1, const float* __restrict__ bh1,
                                              const float* __restrict__ Wh2, const float* __restrict__ bh2,
                                              float* __restrict__ inp, float* __restrict__ out,
                                              int G, int tstep){
  __shared__ float so[16][256];
  __shared__ float st1[16][H];
  int g0 = blockIdx.x * 16;
  int t = threadIdx.x;
  for (int i = t; i < 16 * H; i += 256){
    int g = i >> 7, c = i & 127;
    int gg = g0 + g;
    so[g][c]       = (gg < G) ? hf[(size_t)gg * H + c] : 0.f;
    so[g][128 + c] = (gg < G) ? hb[(size_t)gg * H + c] : 0.f;
  }
  __syncthreads();
  int j = t & 127;
  int gs = (t >> 7) * 8;
  float a1[8] = {0}, a2[8] = {0};
  for (int k = 0; k < 256; ++k){
    float w1 = Wh1[k * H + j];
    float w2 = Wred[k * H + j];
#pragma unroll
    for (int g = 0; g < 8; ++g){
      float o = so[gs + g][k];
      a1[g] += o * w1;
      a2[g] += o * w2;
    }
  }
  float B1 = bh1[j], BR = bred[j];
#pragma unroll
  for (int g = 0; g < 8; ++g){
    int gg = g0 + gs + g;
    float t1 = fmaxf(a1[g] + B1, 0.f);
    st1[gs + g][j] = (gg < G) ? t1 : 0.f;
    if (gg < G) inp[(size_t)gg * H + j] = a2[g] + BR;
  }
  __syncthreads();
  if (t < 32){
    int g = t >> 1, o = t & 1;
    int gg = g0 + g;
    if (gg < G){
      float s = bh2[o];
#pragma unroll 8
      for (int k = 0; k < H; ++k) s += st1[g][k] * Wh2[k * 2 + o];
      out[((size_t)gg * GAPLEN + tstep) * 2 + o] = s;
    }
  }
}

// =======================================================================
extern "C" void kernel_launch(void* const* d_in, const int* in_sizes, int n_in,
                              void* d_out, int out_size, void* d_ws, size_t ws_size,
                              hipStream_t stream) {
  const float* x     = (const float*)d_in[0];
  const int*   ei    = (const int*)d_in[1];
  const int*   batch = (const int*)d_in[2];
  const float* semb  = (const float*)d_in[3];
  const float* nemb  = (const float*)d_in[4];
  const float* W1 = (const float*)d_in[5];  const float* b1 = (const float*)d_in[6];
  const float* W2 = (const float*)d_in[7];  const float* b2 = (const float*)d_in[8];
  const float* W3 = (const float*)d_in[9];  const float* b3 = (const float*)d_in[10];
  const float* Wih_f = (const float*)d_in[11]; const float* Whh_f = (const float*)d_in[12];
  const float* bih_f = (const float*)d_in[13]; const float* bhh_f = (const float*)d_in[14];
  const float* Wih_b = (const float*)d_in[15]; const float* Whh_b = (const float*)d_in[16];
  const float* bih_b = (const float*)d_in[17]; const float* bhh_b = (const float*)d_in[18];
  const float* Wred = (const float*)d_in[19]; const float* bred = (const float*)d_in[20];
  const float* Wh1  = (const float*)d_in[21]; const float* bh1  = (const float*)d_in[22];
  const float* Wh2  = (const float*)d_in[23]; const float* bh2  = (const float*)d_in[24];
  const int* gap = (const int*)d_in[26];

  int N = in_sizes[0] / 12;
  int E = in_sizes[1] / 2;
  int G = out_size / (GAPLEN * 2);
  int NB = ceil_div(N, 128);   // dst buckets (<=1024 for N<=131072)
  float* out = (float*)d_out;

  char* ws = (char*)d_ws;
  size_t off = 0;
  auto alloc = [&](size_t bytes) -> void* {
    void* p = ws + off;
    off += (bytes + 511) & ~(size_t)511;
    return p;
  };
  float* feats  = (float*)alloc((size_t)N * DIN * 4);
  float* bufA   = (float*)alloc((size_t)N * H * 4);
  float* bufB   = (float*)alloc((size_t)N * H * 4);
  int*   cnt    = (int*)alloc((size_t)N * 4);
  float* dis    = (float*)alloc((size_t)N * 4);
  int*   rp     = (int*)alloc((size_t)N * 4);
  int*   csr    = (int*)alloc((size_t)E * 4);
  int*   ebuf   = (int*)alloc((size_t)E * 4);
  int*   bh     = (int*)alloc((size_t)NB * 4);
  int*   bbase  = (int*)alloc((size_t)NB * 4);
  int*   bcur   = (int*)alloc((size_t)NB * 4);
  int*   gc     = (int*)alloc((size_t)G * 4);
  int*   go     = (int*)alloc((size_t)G * 4);
  float* ginp   = (float*)alloc((size_t)G * H * 4);
  float* ghf    = (float*)alloc((size_t)G * H * 4);
  float* ghb    = (float*)alloc((size_t)G * H * 4);
  (void)ws_size; (void)n_in;

  hipMemsetAsync(bh, 0, (size_t)NB * 4, stream);
  hipMemsetAsync(bcur, 0, (size_t)NB * 4, stream);
  hipMemsetAsync(gc, 0, (size_t)G * 4, stream);

  int nb256 = ceil_div(N, 256);
  int ebC   = ceil_div(E, CHUNK);

  build_feats_k<<<nb256, 256, 0, stream>>>(x, semb, nemb, feats, N);
  bhistA_k<<<ebC, 256, 0, stream>>>(ei, bh, E, NB);
  bscan_k<<<1, 1024, 0, stream>>>(bh, bbase, NB);
  bpartC_k<<<ebC, 256, 0, stream>>>(ei, bbase, bcur, ebuf, E, NB);
  bbuildD_k<<<NB, 256, 0, stream>>>(ebuf, bh, bbase, rp, cnt, dis, csr, N);

  int aggb  = ceil_div(N, 8);
  int aggbs = 8 * ceil_div(N, 16);
  // layer 1: aggregate feats (18), GEMM 18->128 (+relu)
  agg18_k<<<aggb, 256, 0, stream>>>(feats, dis, rp, cnt, csr, bufA, N);
  gemm18_k<<<ceil_div(N, 8), 256, 0, stream>>>(bufA, W1, b1, bufB, N);
  // layer 2
  agg128s_k<<<aggbs, 256, 0, stream>>>(bufB, dis, rp, cnt, csr, bufA, N);
  gemm128_k<<<ceil_div(N, 64), 128, 0, stream>>>(bufA, W2, b2, bufB, N);
  // layer 3
  agg128s_k<<<aggbs, 256, 0, stream>>>(bufB, dis, rp, cnt, csr, bufA, N);
  gemm128_k<<<ceil_div(N, 64), 128, 0, stream>>>(bufA, W3, b3, bufB, N);

  // gap-node gather
  ghist_k<<<nb256, 256, 0, stream>>>(batch, gc, N);
  gscan_k<<<1, 1024, 0, stream>>>(gc, go, G);
  gather_k<<<G, H, 0, stream>>>(bufB, go, gap, ginp, ghf, ghb, G);

  // decoder: 3 steps
  int gb = ceil_div(G, 16);
  for (int t = 0; t < GAPLEN; ++t){
    gru_k<<<dim3(gb, 2), 256, 0, stream>>>(ginp, ghf, ghb,
                                           Wih_f, Whh_f, bih_f, bhh_f,
                                           Wih_b, Whh_b, bih_b, bhh_b, G);
    post_k<<<gb, 256, 0, stream>>>(ghf, ghb, Wred, bred, Wh1, bh1, Wh2, bh2,
                                   ginp, out, G, t);
  }
}

// Round 3
// 1018.687 us; speedup vs baseline: 1.1106x; 1.1106x over previous
//
#include <hip/hip_runtime.h>
#include <math.h>

// N=100000 nodes, E=1600000 edges, F_IN=10 (+2 idx cols), H=128, G=1000 graphs, GAP=3
#define H 128
#define GAPLEN 3
#define DIN 18   // 10 float feats + 4 ship emb + 4 nav emb

static inline int ceil_div(int a, int b){ return (a + b - 1) / b; }

// ---------------- feats (PRE-SCALED by dis[i]) ----------------
__global__ void build_feats_k(const float* __restrict__ x, const float* __restrict__ se,
                              const float* __restrict__ ne, const float* __restrict__ dis,
                              float* __restrict__ f, int n){
  int i = blockIdx.x * 256 + threadIdx.x;
  if (i >= n) return;
  const float* xr = x + (size_t)i * 12;
  float* fr = f + (size_t)i * DIN;
  float di = dis[i];
#pragma unroll
  for (int c = 0; c < 10; ++c) fr[c] = di * xr[c];
  int st = (int)xr[10];
  int nv = (int)xr[11];
#pragma unroll
  for (int c = 0; c < 4; ++c){
    fr[10 + c] = di * se[st * 4 + c];
    fr[14 + c] = di * ne[nv * 4 + c];
  }
}

// =================== bucketed CSR build (round-2, kept: saved ~138us) ===================
#define CHUNK 4096

__global__ __launch_bounds__(256) void bhistA_k(const int* __restrict__ ei, int* __restrict__ bh,
                                                int E, int NB){
  __shared__ int lh[1024];
  int t = threadIdx.x;
  for (int j = t; j < 1024; j += 256) lh[j] = 0;
  __syncthreads();
  int base = blockIdx.x * CHUNK;
#pragma unroll
  for (int i = 0; i < 16; ++i){
    int e = base + i * 256 + t;
    if (e < E) atomicAdd(&lh[ei[E + e] >> 7], 1);
  }
  __syncthreads();
  for (int j = t; j < NB; j += 256){
    int v = lh[j];
    if (v) atomicAdd(&bh[j], v);
  }
}

__global__ void bscan_k(const int* __restrict__ bh, int* __restrict__ bbase, int NB){
  __shared__ int sd[1024];
  int t = threadIdx.x;
  int v = (t < NB) ? bh[t] : 0;
  sd[t] = v;
  __syncthreads();
  for (int off = 1; off < 1024; off <<= 1){
    int add = (t >= off) ? sd[t - off] : 0;
    __syncthreads();
    sd[t] += add;
    __syncthreads();
  }
  if (t < NB) bbase[t] = sd[t] - v;
}

__global__ __launch_bounds__(256) void bpartC_k(const int* __restrict__ ei,
                                                const int* __restrict__ bbase,
                                                int* __restrict__ bcur,
                                                int* __restrict__ ebuf, int E, int NB){
  __shared__ int lh[1024];
  __shared__ int lchunk[1024];
  __shared__ int lcur[1024];
  int t = threadIdx.x;
  for (int j = t; j < 1024; j += 256) lh[j] = 0;
  __syncthreads();
  int base = blockIdx.x * CHUNK;
  int pk[16], bk[16];
#pragma unroll
  for (int i = 0; i < 16; ++i){
    int e = base + i * 256 + t;
    if (e < E){
      int s = ei[e];
      int d = ei[E + e];
      bk[i] = d >> 7;
      pk[i] = ((d & 127) << 17) | s;
      atomicAdd(&lh[bk[i]], 1);
    } else bk[i] = -1;
  }
  __syncthreads();
  for (int j = t; j < NB; j += 256){
    int c = lh[j];
    if (c) lchunk[j] = bbase[j] + atomicAdd(&bcur[j], c);
    lcur[j] = 0;
  }
  __syncthreads();
#pragma unroll
  for (int i = 0; i < 16; ++i){
    if (bk[i] >= 0){
      int off = atomicAdd(&lcur[bk[i]], 1);
      ebuf[lchunk[bk[i]] + off] = pk[i];
    }
  }
}

__global__ __launch_bounds__(256) void bbuildD_k(const int* __restrict__ ebuf,
                                                 const int* __restrict__ bh,
                                                 const int* __restrict__ bbase,
                                                 int* __restrict__ rp, int* __restrict__ cnt,
                                                 float* __restrict__ dis, int* __restrict__ csr,
                                                 int n){
  __shared__ int hist[128], sc[128], gb[128], curr[128];
  int b = blockIdx.x;
  int t = threadIdx.x;
  int sb = bbase[b];
  int mb = bh[b];
  if (t < 128) hist[t] = 0;
  __syncthreads();
  for (int i = t; i < mb; i += 256)
    atomicAdd(&hist[ebuf[sb + i] >> 17], 1);
  __syncthreads();
  if (t < 128) sc[t] = hist[t];
  __syncthreads();
  for (int off = 1; off < 128; off <<= 1){
    int add = (t < 128 && t >= off) ? sc[t - off] : 0;
    __syncthreads();
    if (t < 128) sc[t] += add;
    __syncthreads();
  }
  if (t < 128){
    int node = b * 128 + t;
    int rpv = sb + sc[t] - hist[t];
    gb[t] = rpv;
    curr[t] = 0;
    if (node < n){
      rp[node] = rpv;
      cnt[node] = hist[t];
      dis[node] = rsqrtf((float)hist[t] + 1.0f);
    }
  }
  __syncthreads();
  for (int i = t; i < mb; i += 256){
    int p = ebuf[sb + i];
    int dl = p >> 17;
    int src = p & 0x1FFFF;
    int off = atomicAdd(&curr[dl], 1);
    csr[gb[dl] + off] = src;
  }
}

// ---------------- aggregation, d=18, feats pre-scaled ----------------
// out[i] = dis[i] * (sum_src fw[src] + fw[i]); row-major out [N,18]
__global__ void agg18_k(const float* __restrict__ fw, const float* __restrict__ dis,
                        const int* __restrict__ rp, const int* __restrict__ cnt,
                        const int* __restrict__ csr, float* __restrict__ out, int n){
  int node = blockIdx.x * 8 + (threadIdx.x >> 5);
  if (node >= n) return;
  int lane = threadIdx.x & 31;
  bool act = lane < DIN;
  int start = rp[node];
  int m = cnt[node];
  float acc = 0.f;
  for (int e = 0; e < m; ++e){
    int s = csr[start + e];
    if (act) acc += fw[(size_t)s * DIN + lane];
  }
  float di = dis[node];
  if (act){
    float self = fw[(size_t)node * DIN + lane];
    out[(size_t)node * DIN + lane] = di * (acc + self);
  }
}

// ---------------- aggregation, d=128, SLICED layout, XCD-phased ----------------
// hs layout: [16][N][8] floats (slice = col/8). Slice = 3.2MB < 4MiB L2/XCD.
// Grid: first 8*TB blocks -> slices 0..7 (one per XCD via bid%8), then 8..15.
// hs values are pre-scaled by dis[src]; out_i = dis_i*(acc + hs_i) (unscaled).
__global__ __launch_bounds__(256) void agg128sl_k(const float* __restrict__ hs,
                                                  const float* __restrict__ dis,
                                                  const int* __restrict__ rp,
                                                  const int* __restrict__ cnt,
                                                  const int* __restrict__ csr,
                                                  float* __restrict__ outs, int n, int TB){
  int bid = blockIdx.x;
  int half = TB * 8;
  int slice, tile;
  if (bid < half){ slice = bid & 7;       tile = bid >> 3; }
  else           { int b2 = bid - half; slice = 8 + (b2 & 7); tile = b2 >> 3; }
  int t = threadIdx.x;
  int node = tile * 32 + (t >> 3);
  if (node >= n) return;
  int lane = t & 7;
  const float* hsS = hs   + (size_t)slice * n * 8;
  float*       oS  = outs + (size_t)slice * n * 8;
  int start = rp[node];
  int m = cnt[node];
  float acc = 0.f;
  for (int e0 = 0; e0 < m; e0 += 8){
    int r = m - e0;
    int sv = csr[start + e0 + (lane < r ? lane : 0)];
    if (r >= 8){
#pragma unroll
      for (int j = 0; j < 8; ++j){
        int s = __shfl(sv, j, 8);
        acc += hsS[(size_t)s * 8 + lane];
      }
    } else {
      for (int j = 0; j < r; ++j){
        int s = __shfl(sv, j, 8);
        acc += hsS[(size_t)s * 8 + lane];
      }
    }
  }
  float di = dis[node];
  float self = hsS[(size_t)node * 8 + lane];
  oS[(size_t)node * 8 + lane] = di * (acc + self);
}

// ---------------- GEMM: [n,18] @ [18,128] + bias, relu, x dis -> SLICED out ----------------
__global__ void gemm18_k(const float* __restrict__ A, const float* __restrict__ W,
                         const float* __restrict__ b, const float* __restrict__ dis,
                         float* __restrict__ C, int n){
  __shared__ float sw[DIN * H];
  __shared__ float sb[H];
  __shared__ float sa[8][DIN];
  int t = threadIdx.x;
  for (int i = t; i < DIN * H; i += 256) sw[i] = W[i];
  if (t < H) sb[t] = b[t];
  int row0 = blockIdx.x * 8;
  for (int i = t; i < 8 * DIN; i += 256){
    int r = i / DIN, c = i % DIN;
    int rr = row0 + r;
    sa[r][c] = (rr < n) ? A[(size_t)rr * DIN + c] : 0.f;
  }
  __syncthreads();
  int r = t >> 5, lane = t & 31;
  int row = row0 + r;
  if (row >= n) return;
  int c0 = lane * 4;
  float ox = sb[c0], oy = sb[c0 + 1], oz = sb[c0 + 2], ow = sb[c0 + 3];
#pragma unroll
  for (int k = 0; k < DIN; ++k){
    float a = sa[r][k];
    const float4 w = *(const float4*)&sw[k * H + c0];
    ox += a * w.x; oy += a * w.y; oz += a * w.z; ow += a * w.w;
  }
  float di = dis[row];
  float4 o;
  o.x = di * fmaxf(ox, 0.f); o.y = di * fmaxf(oy, 0.f);
  o.z = di * fmaxf(oz, 0.f); o.w = di * fmaxf(ow, 0.f);
  *(float4*)&C[((size_t)(c0 >> 3) * n + row) * 8 + (c0 & 7)] = o;
}

// ---------------- GEMM: [n,128](SLICED A) @ [128,128] + bias, relu ----------------
// OUTMODE 0: sliced out, scaled by dis.  OUTMODE 1: row-major out, unscaled.
template<int OUTMODE>
__global__ __launch_bounds__(128) void gemm128_k(const float* __restrict__ A,
                                                 const float* __restrict__ B,
                                                 const float* __restrict__ bias,
                                                 const float* __restrict__ dis,
                                                 float* __restrict__ C, int n){
  __shared__ float sa[32][64];  // [k][row]
  int t = threadIdx.x;
  int row0 = blockIdx.x * 64;
  int tc = t & 15;
  int tr = t >> 4;
  float acc[8][8];
#pragma unroll
  for (int i = 0; i < 8; ++i)
#pragma unroll
    for (int j = 0; j < 8; ++j) acc[i][j] = 0.f;

  int lr = t >> 1;
  int lc = (t & 1) * 16;
  for (int k0 = 0; k0 < H; k0 += 32){
    int row = row0 + lr;
    bool rowok = row < n;
    int sl = (k0 + lc) >> 3;
    float4 v0, v1, v2, v3;
    if (rowok){
      const float* Ap0 = A + ((size_t)sl * n + row) * 8;
      const float* Ap1 = A + ((size_t)(sl + 1) * n + row) * 8;
      v0 = *(const float4*)(Ap0);
      v1 = *(const float4*)(Ap0 + 4);
      v2 = *(const float4*)(Ap1);
      v3 = *(const float4*)(Ap1 + 4);
    } else {
      v0 = v1 = v2 = v3 = float4{0.f, 0.f, 0.f, 0.f};
    }
    __syncthreads();
    float vv[16] = {v0.x, v0.y, v0.z, v0.w, v1.x, v1.y, v1.z, v1.w,
                    v2.x, v2.y, v2.z, v2.w, v3.x, v3.y, v3.z, v3.w};
#pragma unroll
    for (int i = 0; i < 16; ++i) sa[lc + i][lr] = vv[i];
    __syncthreads();

    const float* Bp = B + (size_t)k0 * H + tc * 8;
#pragma unroll
    for (int k = 0; k < 32; ++k){
      float4 b0 = *(const float4*)(Bp + (size_t)k * H);
      float4 b1 = *(const float4*)(Bp + (size_t)k * H + 4);
      float4 a0 = *(const float4*)&sa[k][tr * 8];
      float4 a1 = *(const float4*)&sa[k][tr * 8 + 4];
      float aa[8] = {a0.x, a0.y, a0.z, a0.w, a1.x, a1.y, a1.z, a1.w};
      float bb[8] = {b0.x, b0.y, b0.z, b0.w, b1.x, b1.y, b1.z, b1.w};
#pragma unroll
      for (int i = 0; i < 8; ++i)
#pragma unroll
        for (int j = 0; j < 8; ++j) acc[i][j] += aa[i] * bb[j];
    }
  }
  float bb[8];
#pragma unroll
  for (int j = 0; j < 8; ++j) bb[j] = bias[tc * 8 + j];
#pragma unroll
  for (int i = 0; i < 8; ++i){
    int row = row0 + tr * 8 + i;
    if (row < n){
      float4 o0, o1;
      o0.x = fmaxf(acc[i][0] + bb[0], 0.f);
      o0.y = fmaxf(acc[i][1] + bb[1], 0.f);
      o0.z = fmaxf(acc[i][2] + bb[2], 0.f);
      o0.w = fmaxf(acc[i][3] + bb[3], 0.f);
      o1.x = fmaxf(acc[i][4] + bb[4], 0.f);
      o1.y = fmaxf(acc[i][5] + bb[5], 0.f);
      o1.z = fmaxf(acc[i][6] + bb[6], 0.f);
      o1.w = fmaxf(acc[i][7] + bb[7], 0.f);
      if (OUTMODE == 0){
        float di = dis[row];
        o0.x *= di; o0.y *= di; o0.z *= di; o0.w *= di;
        o1.x *= di; o1.y *= di; o1.z *= di; o1.w *= di;
        float* Cp = C + ((size_t)tc * n + row) * 8;
        *(float4*)(Cp) = o0;
        *(float4*)(Cp + 4) = o1;
      } else {
        float* Cp = C + (size_t)row * H + tc * 8;
        *(float4*)(Cp) = o0;
        *(float4*)(Cp + 4) = o1;
      }
    }
  }
}

// ---------------- graph counts histogram + scan + gap gather ----------------
__global__ void ghist_k(const int* __restrict__ batch, int* __restrict__ gc, int n){
  int i = blockIdx.x * 256 + threadIdx.x;
  if (i < n) atomicAdd(&gc[batch[i]], 1);
}

__global__ void gscan_k(const int* __restrict__ gc, int* __restrict__ go, int G){
  __shared__ int sd[1024];
  int t = threadIdx.x;
  int v = (t < G) ? gc[t] : 0;
  sd[t] = v;
  __syncthreads();
  for (int off = 1; off < 1024; off <<= 1){
    int add = (t >= off) ? sd[t - off] : 0;
    __syncthreads();
    sd[t] += add;
    __syncthreads();
  }
  if (t < G) go[t] = sd[t] - v;
}

__global__ void gather_k(const float* __restrict__ h, const int* __restrict__ go,
                         const int* __restrict__ gap, float* __restrict__ inp,
                         float* __restrict__ hf, float* __restrict__ hb, int G){
  int g = blockIdx.x;
  int t = threadIdx.x;
  if (g >= G) return;
  int idx = go[g] + gap[0];
  float v = h[(size_t)idx * H + t];
  inp[(size_t)g * H + t] = v;
  hf[(size_t)g * H + t] = v;
  hb[(size_t)g * H + t] = v;
}

// ---------------- GRU step ----------------
__global__ __launch_bounds__(256) void gru_k(const float* __restrict__ inp,
                                             float* __restrict__ hf, float* __restrict__ hb,
                                             const float* __restrict__ Wih_f, const float* __restrict__ Whh_f,
                                             const float* __restrict__ bih_f, const float* __restrict__ bhh_f,
                                             const float* __restrict__ Wih_b, const float* __restrict__ Whh_b,
                                             const float* __restrict__ bih_b, const float* __restrict__ bhh_b,
                                             int G){
  int cell = blockIdx.y;
  const float* Wih = cell ? Wih_b : Wih_f;
  const float* Whh = cell ? Whh_b : Whh_f;
  const float* bih = cell ? bih_b : bih_f;
  const float* bhh = cell ? bhh_b : bhh_f;
  float* h = cell ? hb : hf;

  __shared__ float sx[16][H];
  __shared__ float sh[16][H];
  int g0 = blockIdx.x * 16;
  int t = threadIdx.x;
  for (int i = t; i < 16 * H; i += 256){
    int g = i >> 7, c = i & 127;
    int gg = g0 + g;
    sx[g][c] = (gg < G) ? inp[(size_t)gg * H + c] : 0.f;
    sh[g][c] = (gg < G) ? h[(size_t)gg * H + c] : 0.f;
  }
  __syncthreads();
  int j = t & 127;
  int gs = (t >> 7) * 8;
  float ar[8] = {0}, az[8] = {0}, an[8] = {0};
  float br[8] = {0}, bz[8] = {0}, bn[8] = {0};
  for (int k = 0; k < H; ++k){
    float wr = Wih[k * 384 + j];
    float wz = Wih[k * 384 + 128 + j];
    float wn = Wih[k * 384 + 256 + j];
    float ur = Whh[k * 384 + j];
    float uz = Whh[k * 384 + 128 + j];
    float un = Whh[k * 384 + 256 + j];
#pragma unroll
    for (int g = 0; g < 8; ++g){
      float xv = sx[gs + g][k];
      float hv = sh[gs + g][k];
      ar[g] += xv * wr; az[g] += xv * wz; an[g] += xv * wn;
      br[g] += hv * ur; bz[g] += hv * uz; bn[g] += hv * un;
    }
  }
  float bir = bih[j], biz = bih[128 + j], bin = bih[256 + j];
  float bhr = bhh[j], bhz = bhh[128 + j], bhn = bhh[256 + j];
#pragma unroll
  for (int g = 0; g < 8; ++g){
    int gg = g0 + gs + g;
    if (gg < G){
      float r = 1.f / (1.f + expf(-(ar[g] + bir + br[g] + bhr)));
      float z = 1.f / (1.f + expf(-(az[g] + biz + bz[g] + bhz)));
      float nn = tanhf(an[g] + bin + r * (bn[g] + bhn));
      float hv = sh[gs + g][j];
      h[(size_t)gg * H + j] = (1.f - z) * nn + z * hv;
    }
  }
}

// ---------------- post step ----------------
__global__ __launch_bounds__(256) void post_k(const float* __restrict__ hf, const float* __restrict__ hb,
                                              const float* __restrict__ Wred, const float* __restrict__ bred,
                                              const float* __restrict__ Wh1, const float* __restrict__ bh1,
                                              const float* __restrict__ Wh2, const float* __restrict__ bh2,
                                              float* __restrict__ inp, float* __restrict__ out,
                                              int G, int tstep){
  __shared__ float so[16][256];
  __shared__ float st1[16][H];
  int g0 = blockIdx.x * 16;
  int t = threadIdx.x;
  for (int i = t; i < 16 * H; i += 256){
    int g = i >> 7, c = i & 127;
    int gg = g0 + g;
    so[g][c]       = (gg < G) ? hf[(size_t)gg * H + c] : 0.f;
    so[g][128 + c] = (gg < G) ? hb[(size_t)gg * H + c] : 0.f;
  }
  __syncthreads();
  int j = t & 127;
  int gs = (t >> 7) * 8;
  float a1[8] = {0}, a2[8] = {0};
  for (int k = 0; k < 256; ++k){
    float w1 = Wh1[k * H + j];
    float w2 = Wred[k * H + j];
#pragma unroll
    for (int g = 0; g < 8; ++g){
      float o = so[gs + g][k];
      a1[g] += o * w1;
      a2[g] += o * w2;
    }
  }
  float B1 = bh1[j], BR = bred[j];
#pragma unroll
  for (int g = 0; g < 8; ++g){
    int gg = g0 + gs + g;
    float t1 = fmaxf(a1[g] + B1, 0.f);
    st1[gs + g][j] = (gg < G) ? t1 : 0.f;
    if (gg < G) inp[(size_t)gg * H + j] = a2[g] + BR;
  }
  __syncthreads();
  if (t < 32){
    int g = t >> 1, o = t & 1;
    int gg = g0 + g;
    if (gg < G){
      float s = bh2[o];
#pragma unroll 8
      for (int k = 0; k < H; ++k) s += st1[g][k] * Wh2[k * 2 + o];
      out[((size_t)gg * GAPLEN + tstep) * 2 + o] = s;
    }
  }
}

// =======================================================================
extern "C" void kernel_launch(void* const* d_in, const int* in_sizes, int n_in,
                              void* d_out, int out_size, void* d_ws, size_t ws_size,
                              hipStream_t stream) {
  const float* x     = (const float*)d_in[0];
  const int*   ei    = (const int*)d_in[1];
  const int*   batch = (const int*)d_in[2];
  const float* semb  = (const float*)d_in[3];
  const float* nemb  = (const float*)d_in[4];
  const float* W1 = (const float*)d_in[5];  const float* b1 = (const float*)d_in[6];
  const float* W2 = (const float*)d_in[7];  const float* b2 = (const float*)d_in[8];
  const float* W3 = (const float*)d_in[9];  const float* b3 = (const float*)d_in[10];
  const float* Wih_f = (const float*)d_in[11]; const float* Whh_f = (const float*)d_in[12];
  const float* bih_f = (const float*)d_in[13]; const float* bhh_f = (const float*)d_in[14];
  const float* Wih_b = (const float*)d_in[15]; const float* Whh_b = (const float*)d_in[16];
  const float* bih_b = (const float*)d_in[17]; const float* bhh_b = (const float*)d_in[18];
  const float* Wred = (const float*)d_in[19]; const float* bred = (const float*)d_in[20];
  const float* Wh1  = (const float*)d_in[21]; const float* bh1  = (const float*)d_in[22];
  const float* Wh2  = (const float*)d_in[23]; const float* bh2  = (const float*)d_in[24];
  const int* gap = (const int*)d_in[26];

  int N = in_sizes[0] / 12;
  int E = in_sizes[1] / 2;
  int G = out_size / (GAPLEN * 2);
  int NB = ceil_div(N, 128);
  float* out = (float*)d_out;

  char* ws = (char*)d_ws;
  size_t off = 0;
  auto alloc = [&](size_t bytes) -> void* {
    void* p = ws + off;
    off += (bytes + 511) & ~(size_t)511;
    return p;
  };
  float* feats  = (float*)alloc((size_t)N * DIN * 4);
  float* agg1   = (float*)alloc((size_t)N * DIN * 4);  // agg18 output, row-major [N,18]
  float* sl1    = (float*)alloc((size_t)N * H * 4);    // sliced buffer A (also reused as row-major h3)
  float* sl2    = (float*)alloc((size_t)N * H * 4);    // sliced buffer B
  int*   cnt    = (int*)alloc((size_t)N * 4);
  float* dis    = (float*)alloc((size_t)N * 4);
  int*   rp     = (int*)alloc((size_t)N * 4);
  int*   csr    = (int*)alloc((size_t)E * 4);
  int*   ebuf   = (int*)alloc((size_t)E * 4);
  int*   bh     = (int*)alloc((size_t)NB * 4);
  int*   bbase  = (int*)alloc((size_t)NB * 4);
  int*   bcur   = (int*)alloc((size_t)NB * 4);
  int*   gc     = (int*)alloc((size_t)G * 4);
  int*   go     = (int*)alloc((size_t)G * 4);
  float* ginp   = (float*)alloc((size_t)G * H * 4);
  float* ghf    = (float*)alloc((size_t)G * H * 4);
  float* ghb    = (float*)alloc((size_t)G * H * 4);
  (void)ws_size; (void)n_in;

  hipMemsetAsync(bh, 0, (size_t)NB * 4, stream);
  hipMemsetAsync(bcur, 0, (size_t)NB * 4, stream);
  hipMemsetAsync(gc, 0, (size_t)G * 4, stream);

  int nb256 = ceil_div(N, 256);
  int ebC   = ceil_div(E, CHUNK);

  // CSR build first (produces dis), then pre-scaled feats
  bhistA_k<<<ebC, 256, 0, stream>>>(ei, bh, E, NB);
  bscan_k<<<1, 1024, 0, stream>>>(bh, bbase, NB);
  bpartC_k<<<ebC, 256, 0, stream>>>(ei, bbase, bcur, ebuf, E, NB);
  bbuildD_k<<<NB, 256, 0, stream>>>(ebuf, bh, bbase, rp, cnt, dis, csr, N);
  build_feats_k<<<nb256, 256, 0, stream>>>(x, semb, nemb, dis, feats, N);

  int TB = ceil_div(N, 32);          // node tiles per slice
  int aggb18 = ceil_div(N, 8);
  int gemmb  = ceil_div(N, 64);

  // layer 1: agg(18) -> gemm18 (sliced+scaled out)
  agg18_k<<<aggb18, 256, 0, stream>>>(feats, dis, rp, cnt, csr, agg1, N);
  gemm18_k<<<aggb18, 256, 0, stream>>>(agg1, W1, b1, dis, sl1, N);
  // layer 2: sliced agg -> gemm (sliced+scaled out)
  agg128sl_k<<<16 * TB, 256, 0, stream>>>(sl1, dis, rp, cnt, csr, sl2, N, TB);
  gemm128_k<0><<<gemmb, 128, 0, stream>>>(sl2, W2, b2, dis, sl1, N);
  // layer 3: sliced agg -> gemm (row-major out, unscaled) ; write into sl1's space? no: sl1 is input. Use sl2->read, write rowmajor into sl1 after agg consumed it.
  agg128sl_k<<<16 * TB, 256, 0, stream>>>(sl1, dis, rp, cnt, csr, sl2, N, TB);
  gemm128_k<1><<<gemmb, 128, 0, stream>>>(sl2, W3, b3, dis, sl1, N);  // sl1 now row-major h3

  // gap-node gather
  ghist_k<<<nb256, 256, 0, stream>>>(batch, gc, N);
  gscan_k<<<1, 1024, 0, stream>>>(gc, go, G);
  gather_k<<<G, H, 0, stream>>>(sl1, go, gap, ginp, ghf, ghb, G);

  // decoder: 3 steps
  int gb = ceil_div(G, 16);
  for (int t = 0; t < GAPLEN; ++t){
    gru_k<<<dim3(gb, 2), 256, 0, stream>>>(ginp, ghf, ghb,
                                           Wih_f, Whh_f, bih_f, bhh_f,
                                           Wih_b, Whh_b, bih_b, bhh_b, G);
    post_k<<<gb, 256, 0, stream>>>(ghf, ghb, Wred, bred, Wh1, bh1, Wh2, bh2,
                                   ginp, out, G, t);
  }
}

// Round 4
// 933.551 us; speedup vs baseline: 1.2118x; 1.0912x over previous
//
#include <hip/hip_runtime.h>
#include <math.h>

// N=100000 nodes, E=1600000 edges, F_IN=10 (+2 idx cols), H=128, G=1000 graphs, GAP=3
#define H 128
#define GAPLEN 3
#define DIN 18   // 10 float feats + 4 ship emb + 4 nav emb

static inline int ceil_div(int a, int b){ return (a + b - 1) / b; }

// ---------------- feats (PRE-SCALED by dis[i]) -> SLICED [3][N][8], cols 18..23 = 0 ----------------
__global__ void build_feats_k(const float* __restrict__ x, const float* __restrict__ se,
                              const float* __restrict__ ne, const float* __restrict__ dis,
                              float* __restrict__ fs, int n){
  int i = blockIdx.x * 256 + threadIdx.x;
  if (i >= n) return;
  const float* xr = x + (size_t)i * 12;
  float di = dis[i];
  float v[24];
#pragma unroll
  for (int c = 0; c < 10; ++c) v[c] = di * xr[c];
  int st = (int)xr[10];
  int nv = (int)xr[11];
#pragma unroll
  for (int c = 0; c < 4; ++c){
    v[10 + c] = di * se[st * 4 + c];
    v[14 + c] = di * ne[nv * 4 + c];
  }
#pragma unroll
  for (int c = 18; c < 24; ++c) v[c] = 0.f;
#pragma unroll
  for (int s = 0; s < 3; ++s){
    float* p = fs + ((size_t)s * n + i) * 8;
    *(float4*)(p)     = float4{v[s*8+0], v[s*8+1], v[s*8+2], v[s*8+3]};
    *(float4*)(p + 4) = float4{v[s*8+4], v[s*8+5], v[s*8+6], v[s*8+7]};
  }
}

// =================== bucketed CSR build (kept) ===================
#define CHUNK 4096

__global__ __launch_bounds__(256) void bhistA_k(const int* __restrict__ ei, int* __restrict__ bh,
                                                int E, int NB){
  __shared__ int lh[1024];
  int t = threadIdx.x;
  for (int j = t; j < 1024; j += 256) lh[j] = 0;
  __syncthreads();
  int base = blockIdx.x * CHUNK;
#pragma unroll
  for (int i = 0; i < 16; ++i){
    int e = base + i * 256 + t;
    if (e < E) atomicAdd(&lh[ei[E + e] >> 7], 1);
  }
  __syncthreads();
  for (int j = t; j < NB; j += 256){
    int v = lh[j];
    if (v) atomicAdd(&bh[j], v);
  }
}

__global__ void bscan_k(const int* __restrict__ bh, int* __restrict__ bbase, int NB){
  __shared__ int sd[1024];
  int t = threadIdx.x;
  int v = (t < NB) ? bh[t] : 0;
  sd[t] = v;
  __syncthreads();
  for (int off = 1; off < 1024; off <<= 1){
    int add = (t >= off) ? sd[t - off] : 0;
    __syncthreads();
    sd[t] += add;
    __syncthreads();
  }
  if (t < NB) bbase[t] = sd[t] - v;
}

__global__ __launch_bounds__(256) void bpartC_k(const int* __restrict__ ei,
                                                const int* __restrict__ bbase,
                                                int* __restrict__ bcur,
                                                int* __restrict__ ebuf, int E, int NB){
  __shared__ int lh[1024];
  __shared__ int lchunk[1024];
  __shared__ int lcur[1024];
  int t = threadIdx.x;
  for (int j = t; j < 1024; j += 256) lh[j] = 0;
  __syncthreads();
  int base = blockIdx.x * CHUNK;
  int pk[16], bk[16];
#pragma unroll
  for (int i = 0; i < 16; ++i){
    int e = base + i * 256 + t;
    if (e < E){
      int s = ei[e];
      int d = ei[E + e];
      bk[i] = d >> 7;
      pk[i] = ((d & 127) << 17) | s;
      atomicAdd(&lh[bk[i]], 1);
    } else bk[i] = -1;
  }
  __syncthreads();
  for (int j = t; j < NB; j += 256){
    int c = lh[j];
    if (c) lchunk[j] = bbase[j] + atomicAdd(&bcur[j], c);
    lcur[j] = 0;
  }
  __syncthreads();
#pragma unroll
  for (int i = 0; i < 16; ++i){
    if (bk[i] >= 0){
      int off = atomicAdd(&lcur[bk[i]], 1);
      ebuf[lchunk[bk[i]] + off] = pk[i];
    }
  }
}

__global__ __launch_bounds__(256) void bbuildD_k(const int* __restrict__ ebuf,
                                                 const int* __restrict__ bh,
                                                 const int* __restrict__ bbase,
                                                 int* __restrict__ rp, int* __restrict__ cnt,
                                                 float* __restrict__ dis, int* __restrict__ csr,
                                                 int n){
  __shared__ int hist[128], sc[128], gb[128], curr[128];
  int b = blockIdx.x;
  int t = threadIdx.x;
  int sb = bbase[b];
  int mb = bh[b];
  if (t < 128) hist[t] = 0;
  __syncthreads();
  for (int i = t; i < mb; i += 256)
    atomicAdd(&hist[ebuf[sb + i] >> 17], 1);
  __syncthreads();
  if (t < 128) sc[t] = hist[t];
  __syncthreads();
  for (int off = 1; off < 128; off <<= 1){
    int add = (t < 128 && t >= off) ? sc[t - off] : 0;
    __syncthreads();
    if (t < 128) sc[t] += add;
    __syncthreads();
  }
  if (t < 128){
    int node = b * 128 + t;
    int rpv = sb + sc[t] - hist[t];
    gb[t] = rpv;
    curr[t] = 0;
    if (node < n){
      rp[node] = rpv;
      cnt[node] = hist[t];
      dis[node] = rsqrtf((float)hist[t] + 1.0f);
    }
  }
  __syncthreads();
  for (int i = t; i < mb; i += 256){
    int p = ebuf[sb + i];
    int dl = p >> 17;
    int src = p & 0x1FFFF;
    int off = atomicAdd(&curr[dl], 1);
    csr[gb[dl] + off] = src;
  }
}

// ---------------- sliced aggregation, 8-col slices, 2 lanes/node, float4 gathers ----------------
// MODE 0: 16 slices (H=128), 2 phases of 8 (one slice per XCD at a time).
// MODE 1: 4-slice grid over feats [3][N][8]; slice 3 returns immediately.
// hs pre-scaled by dis[src]; out = dis[node]*(sum + self), unscaled.
template<int MODE>
__global__ __launch_bounds__(256) void aggsl_k(const float* __restrict__ hs,
                                               const float* __restrict__ dis,
                                               const int* __restrict__ rp,
                                               const int* __restrict__ cnt,
                                               const int* __restrict__ csr,
                                               float* __restrict__ outs, int n, int TB){
  int bid = blockIdx.x;
  int slice, tile;
  if (MODE == 0){
    int per_phase = TB * 8;
    int phase = bid < per_phase ? 0 : 1;
    int rem = bid - phase * per_phase;
    slice = phase * 8 + (rem & 7);
    tile  = rem >> 3;
  } else {
    slice = bid & 3;
    if (slice == 3) return;
    tile  = bid >> 2;
  }
  int t = threadIdx.x;
  int node = tile * 128 + (t >> 1);
  if (node >= n) return;
  int half = t & 1;

  const char* bp = (const char*)(hs + (size_t)slice * n * 8) + half * 16;
  int start = rp[node];
  int m = cnt[node];
  float4 a0 = {0.f,0.f,0.f,0.f}, a1 = {0.f,0.f,0.f,0.f};
  int e = 0;
  for (; e + 4 <= m; e += 4){
    int s0 = csr[start + e];
    int s1 = csr[start + e + 1];
    int s2 = csr[start + e + 2];
    int s3 = csr[start + e + 3];
    float4 v0 = *(const float4*)(bp + ((size_t)s0 << 5));
    float4 v1 = *(const float4*)(bp + ((size_t)s1 << 5));
    float4 v2 = *(const float4*)(bp + ((size_t)s2 << 5));
    float4 v3 = *(const float4*)(bp + ((size_t)s3 << 5));
    a0.x += v0.x + v1.x; a0.y += v0.y + v1.y; a0.z += v0.z + v1.z; a0.w += v0.w + v1.w;
    a1.x += v2.x + v3.x; a1.y += v2.y + v3.y; a1.z += v2.z + v3.z; a1.w += v2.w + v3.w;
  }
  for (; e < m; ++e){
    int s = csr[start + e];
    float4 v = *(const float4*)(bp + ((size_t)s << 5));
    a0.x += v.x; a0.y += v.y; a0.z += v.z; a0.w += v.w;
  }
  float4 self = *(const float4*)(bp + ((size_t)node << 5));
  float di = dis[node];
  float4 o;
  o.x = di * (a0.x + a1.x + self.x);
  o.y = di * (a0.y + a1.y + self.y);
  o.z = di * (a0.z + a1.z + self.z);
  o.w = di * (a0.w + a1.w + self.w);
  *(float4*)((char*)(outs + (size_t)slice * n * 8) + half * 16 + ((size_t)node << 5)) = o;
}

// ---------------- GEMM: [n,18](sliced A) @ [18,128] + bias, relu, x dis -> SLICED out ----------------
__global__ void gemm18_k(const float* __restrict__ A, const float* __restrict__ W,
                         const float* __restrict__ b, const float* __restrict__ dis,
                         float* __restrict__ C, int n){
  __shared__ float sw[DIN * H];
  __shared__ float sb[H];
  __shared__ float sa[8][DIN];
  int t = threadIdx.x;
  for (int i = t; i < DIN * H; i += 256) sw[i] = W[i];
  if (t < H) sb[t] = b[t];
  int row0 = blockIdx.x * 8;
  for (int i = t; i < 8 * DIN; i += 256){
    int r = i / DIN, c = i % DIN;
    int rr = row0 + r;
    sa[r][c] = (rr < n) ? A[(((size_t)(c >> 3) * n + rr) << 3) + (c & 7)] : 0.f;
  }
  __syncthreads();
  int r = t >> 5, lane = t & 31;
  int row = row0 + r;
  if (row >= n) return;
  int c0 = lane * 4;
  float ox = sb[c0], oy = sb[c0 + 1], oz = sb[c0 + 2], ow = sb[c0 + 3];
#pragma unroll
  for (int k = 0; k < DIN; ++k){
    float a = sa[r][k];
    const float4 w = *(const float4*)&sw[k * H + c0];
    ox += a * w.x; oy += a * w.y; oz += a * w.z; ow += a * w.w;
  }
  float di = dis[row];
  float4 o;
  o.x = di * fmaxf(ox, 0.f); o.y = di * fmaxf(oy, 0.f);
  o.z = di * fmaxf(oz, 0.f); o.w = di * fmaxf(ow, 0.f);
  *(float4*)&C[(((size_t)(c0 >> 3) * n + row) << 3) + (c0 & 7)] = o;
}

// ---------------- GEMM: [n,128](SLICED A) @ [128,128] + bias, relu ----------------
// OUTMODE 0: sliced out, scaled by dis.  OUTMODE 1: row-major out, unscaled.
template<int OUTMODE>
__global__ __launch_bounds__(128) void gemm128_k(const float* __restrict__ A,
                                                 const float* __restrict__ B,
                                                 const float* __restrict__ bias,
                                                 const float* __restrict__ dis,
                                                 float* __restrict__ C, int n){
  __shared__ float sa[32][64];  // [k][row]
  int t = threadIdx.x;
  int row0 = blockIdx.x * 64;
  int tc = t & 15;
  int tr = t >> 4;
  float acc[8][8];
#pragma unroll
  for (int i = 0; i < 8; ++i)
#pragma unroll
    for (int j = 0; j < 8; ++j) acc[i][j] = 0.f;

  int lr = t >> 1;
  int lc = (t & 1) * 16;
  for (int k0 = 0; k0 < H; k0 += 32){
    int row = row0 + lr;
    bool rowok = row < n;
    int sl = (k0 + lc) >> 3;
    float4 v0, v1, v2, v3;
    if (rowok){
      const float* Ap0 = A + (((size_t)sl * n + row) << 3);
      const float* Ap1 = A + (((size_t)(sl + 1) * n + row) << 3);
      v0 = *(const float4*)(Ap0);
      v1 = *(const float4*)(Ap0 + 4);
      v2 = *(const float4*)(Ap1);
      v3 = *(const float4*)(Ap1 + 4);
    } else {
      v0 = v1 = v2 = v3 = float4{0.f, 0.f, 0.f, 0.f};
    }
    __syncthreads();
    float vv[16] = {v0.x, v0.y, v0.z, v0.w, v1.x, v1.y, v1.z, v1.w,
                    v2.x, v2.y, v2.z, v2.w, v3.x, v3.y, v3.z, v3.w};
#pragma unroll
    for (int i = 0; i < 16; ++i) sa[lc + i][lr] = vv[i];
    __syncthreads();

    const float* Bp = B + (size_t)k0 * H + tc * 8;
#pragma unroll
    for (int k = 0; k < 32; ++k){
      float4 b0 = *(const float4*)(Bp + (size_t)k * H);
      float4 b1 = *(const float4*)(Bp + (size_t)k * H + 4);
      float4 a0 = *(const float4*)&sa[k][tr * 8];
      float4 a1 = *(const float4*)&sa[k][tr * 8 + 4];
      float aa[8] = {a0.x, a0.y, a0.z, a0.w, a1.x, a1.y, a1.z, a1.w};
      float bb[8] = {b0.x, b0.y, b0.z, b0.w, b1.x, b1.y, b1.z, b1.w};
#pragma unroll
      for (int i = 0; i < 8; ++i)
#pragma unroll
        for (int j = 0; j < 8; ++j) acc[i][j] += aa[i] * bb[j];
    }
  }
  float bb[8];
#pragma unroll
  for (int j = 0; j < 8; ++j) bb[j] = bias[tc * 8 + j];
#pragma unroll
  for (int i = 0; i < 8; ++i){
    int row = row0 + tr * 8 + i;
    if (row < n){
      float4 o0, o1;
      o0.x = fmaxf(acc[i][0] + bb[0], 0.f);
      o0.y = fmaxf(acc[i][1] + bb[1], 0.f);
      o0.z = fmaxf(acc[i][2] + bb[2], 0.f);
      o0.w = fmaxf(acc[i][3] + bb[3], 0.f);
      o1.x = fmaxf(acc[i][4] + bb[4], 0.f);
      o1.y = fmaxf(acc[i][5] + bb[5], 0.f);
      o1.z = fmaxf(acc[i][6] + bb[6], 0.f);
      o1.w = fmaxf(acc[i][7] + bb[7], 0.f);
      if (OUTMODE == 0){
        float di = dis[row];
        o0.x *= di; o0.y *= di; o0.z *= di; o0.w *= di;
        o1.x *= di; o1.y *= di; o1.z *= di; o1.w *= di;
        float* Cp = C + (((size_t)tc * n + row) << 3);
        *(float4*)(Cp) = o0;
        *(float4*)(Cp + 4) = o1;
      } else {
        float* Cp = C + (size_t)row * H + tc * 8;
        *(float4*)(Cp) = o0;
        *(float4*)(Cp + 4) = o1;
      }
    }
  }
}

// ---------------- graph counts histogram + scan + gap gather ----------------
__global__ void ghist_k(const int* __restrict__ batch, int* __restrict__ gc, int n){
  int i = blockIdx.x * 256 + threadIdx.x;
  if (i < n) atomicAdd(&gc[batch[i]], 1);
}

__global__ void gscan_k(const int* __restrict__ gc, int* __restrict__ go, int G){
  __shared__ int sd[1024];
  int t = threadIdx.x;
  int v = (t < G) ? gc[t] : 0;
  sd[t] = v;
  __syncthreads();
  for (int off = 1; off < 1024; off <<= 1){
    int add = (t >= off) ? sd[t - off] : 0;
    __syncthreads();
    sd[t] += add;
    __syncthreads();
  }
  if (t < G) go[t] = sd[t] - v;
}

__global__ void gather_k(const float* __restrict__ h, const int* __restrict__ go,
                         const int* __restrict__ gap, float* __restrict__ inp,
                         float* __restrict__ hf, float* __restrict__ hb, int G){
  int g = blockIdx.x;
  int t = threadIdx.x;
  if (g >= G) return;
  int idx = go[g] + gap[0];
  float v = h[(size_t)idx * H + t];
  inp[(size_t)g * H + t] = v;
  hf[(size_t)g * H + t] = v;
  hb[(size_t)g * H + t] = v;
}

// ---------------- GRU step ----------------
__global__ __launch_bounds__(256) void gru_k(const float* __restrict__ inp,
                                             float* __restrict__ hf, float* __restrict__ hb,
                                             const float* __restrict__ Wih_f, const float* __restrict__ Whh_f,
                                             const float* __restrict__ bih_f, const float* __restrict__ bhh_f,
                                             const float* __restrict__ Wih_b, const float* __restrict__ Whh_b,
                                             const float* __restrict__ bih_b, const float* __restrict__ bhh_b,
                                             int G){
  int cell = blockIdx.y;
  const float* Wih = cell ? Wih_b : Wih_f;
  const float* Whh = cell ? Whh_b : Whh_f;
  const float* bih = cell ? bih_b : bih_f;
  const float* bhh = cell ? bhh_b : bhh_f;
  float* h = cell ? hb : hf;

  __shared__ float sx[16][H];
  __shared__ float sh[16][H];
  int g0 = blockIdx.x * 16;
  int t = threadIdx.x;
  for (int i = t; i < 16 * H; i += 256){
    int g = i >> 7, c = i & 127;
    int gg = g0 + g;
    sx[g][c] = (gg < G) ? inp[(size_t)gg * H + c] : 0.f;
    sh[g][c] = (gg < G) ? h[(size_t)gg * H + c] : 0.f;
  }
  __syncthreads();
  int j = t & 127;
  int gs = (t >> 7) * 8;
  float ar[8] = {0}, az[8] = {0}, an[8] = {0};
  float br[8] = {0}, bz[8] = {0}, bn[8] = {0};
  for (int k = 0; k < H; ++k){
    float wr = Wih[k * 384 + j];
    float wz = Wih[k * 384 + 128 + j];
    float wn = Wih[k * 384 + 256 + j];
    float ur = Whh[k * 384 + j];
    float uz = Whh[k * 384 + 128 + j];
    float un = Whh[k * 384 + 256 + j];
#pragma unroll
    for (int g = 0; g < 8; ++g){
      float xv = sx[gs + g][k];
      float hv = sh[gs + g][k];
      ar[g] += xv * wr; az[g] += xv * wz; an[g] += xv * wn;
      br[g] += hv * ur; bz[g] += hv * uz; bn[g] += hv * un;
    }
  }
  float bir = bih[j], biz = bih[128 + j], bin = bih[256 + j];
  float bhr = bhh[j], bhz = bhh[128 + j], bhn = bhh[256 + j];
#pragma unroll
  for (int g = 0; g < 8; ++g){
    int gg = g0 + gs + g;
    if (gg < G){
      float r = 1.f / (1.f + expf(-(ar[g] + bir + br[g] + bhr)));
      float z = 1.f / (1.f + expf(-(az[g] + biz + bz[g] + bhz)));
      float nn = tanhf(an[g] + bin + r * (bn[g] + bhn));
      float hv = sh[gs + g][j];
      h[(size_t)gg * H + j] = (1.f - z) * nn + z * hv;
    }
  }
}

// ---------------- post step ----------------
__global__ __launch_bounds__(256) void post_k(const float* __restrict__ hf, const float* __restrict__ hb,
                                              const float* __restrict__ Wred, const float* __restrict__ bred,
                                              const float* __restrict__ Wh1, const float* __restrict__ bh1,
                                              const float* __restrict__ Wh2, const float* __restrict__ bh2,
                                              float* __restrict__ inp, float* __restrict__ out,
                                              int G, int tstep){
  __shared__ float so[16][256];
  __shared__ float st1[16][H];
  int g0 = blockIdx.x * 16;
  int t = threadIdx.x;
  for (int i = t; i < 16 * H; i += 256){
    int g = i >> 7, c = i & 127;
    int gg = g0 + g;
    so[g][c]       = (gg < G) ? hf[(size_t)gg * H + c] : 0.f;
    so[g][128 + c] = (gg < G) ? hb[(size_t)gg * H + c] : 0.f;
  }
  __syncthreads();
  int j = t & 127;
  int gs = (t >> 7) * 8;
  float a1[8] = {0}, a2[8] = {0};
  for (int k = 0; k < 256; ++k){
    float w1 = Wh1[k * H + j];
    float w2 = Wred[k * H + j];
#pragma unroll
    for (int g = 0; g < 8; ++g){
      float o = so[gs + g][k];
      a1[g] += o * w1;
      a2[g] += o * w2;
    }
  }
  float B1 = bh1[j], BR = bred[j];
#pragma unroll
  for (int g = 0; g < 8; ++g){
    int gg = g0 + gs + g;
    float t1 = fmaxf(a1[g] + B1, 0.f);
    st1[gs + g][j] = (gg < G) ? t1 : 0.f;
    if (gg < G) inp[(size_t)gg * H + j] = a2[g] + BR;
  }
  __syncthreads();
  if (t < 32){
    int g = t >> 1, o = t & 1;
    int gg = g0 + g;
    if (gg < G){
      float s = bh2[o];
#pragma unroll 8
      for (int k = 0; k < H; ++k) s += st1[g][k] * Wh2[k * 2 + o];
      out[((size_t)gg * GAPLEN + tstep) * 2 + o] = s;
    }
  }
}

// =======================================================================
extern "C" void kernel_launch(void* const* d_in, const int* in_sizes, int n_in,
                              void* d_out, int out_size, void* d_ws, size_t ws_size,
                              hipStream_t stream) {
  const float* x     = (const float*)d_in[0];
  const int*   ei    = (const int*)d_in[1];
  const int*   batch = (const int*)d_in[2];
  const float* semb  = (const float*)d_in[3];
  const float* nemb  = (const float*)d_in[4];
  const float* W1 = (const float*)d_in[5];  const float* b1 = (const float*)d_in[6];
  const float* W2 = (const float*)d_in[7];  const float* b2 = (const float*)d_in[8];
  const float* W3 = (const float*)d_in[9];  const float* b3 = (const float*)d_in[10];
  const float* Wih_f = (const float*)d_in[11]; const float* Whh_f = (const float*)d_in[12];
  const float* bih_f = (const float*)d_in[13]; const float* bhh_f = (const float*)d_in[14];
  const float* Wih_b = (const float*)d_in[15]; const float* Whh_b = (const float*)d_in[16];
  const float* bih_b = (const float*)d_in[17]; const float* bhh_b = (const float*)d_in[18];
  const float* Wred = (const float*)d_in[19]; const float* bred = (const float*)d_in[20];
  const float* Wh1  = (const float*)d_in[21]; const float* bh1  = (const float*)d_in[22];
  const float* Wh2  = (const float*)d_in[23]; const float* bh2  = (const float*)d_in[24];
  const int* gap = (const int*)d_in[26];

  int N = in_sizes[0] / 12;
  int E = in_sizes[1] / 2;
  int G = out_size / (GAPLEN * 2);
  int NB = ceil_div(N, 128);
  float* out = (float*)d_out;

  char* ws = (char*)d_ws;
  size_t off = 0;
  auto alloc = [&](size_t bytes) -> void* {
    void* p = ws + off;
    off += (bytes + 511) & ~(size_t)511;
    return p;
  };
  float* feats  = (float*)alloc((size_t)N * 24 * 4);   // sliced [3][N][8]
  float* agg1   = (float*)alloc((size_t)N * 24 * 4);   // sliced [3][N][8]
  float* sl1    = (float*)alloc((size_t)N * H * 4);    // sliced buffer A / final row-major h3
  float* sl2    = (float*)alloc((size_t)N * H * 4);    // sliced buffer B
  int*   cnt    = (int*)alloc((size_t)N * 4);
  float* dis    = (float*)alloc((size_t)N * 4);
  int*   rp     = (int*)alloc((size_t)N * 4);
  int*   csr    = (int*)alloc((size_t)E * 4);
  int*   ebuf   = (int*)alloc((size_t)E * 4);
  int*   bh     = (int*)alloc((size_t)NB * 4);
  int*   bbase  = (int*)alloc((size_t)NB * 4);
  int*   bcur   = (int*)alloc((size_t)NB * 4);
  int*   gc     = (int*)alloc((size_t)G * 4);
  int*   go     = (int*)alloc((size_t)G * 4);
  float* ginp   = (float*)alloc((size_t)G * H * 4);
  float* ghf    = (float*)alloc((size_t)G * H * 4);
  float* ghb    = (float*)alloc((size_t)G * H * 4);
  (void)ws_size; (void)n_in;

  hipMemsetAsync(bh, 0, (size_t)NB * 4, stream);
  hipMemsetAsync(bcur, 0, (size_t)NB * 4, stream);
  hipMemsetAsync(gc, 0, (size_t)G * 4, stream);

  int nb256 = ceil_div(N, 256);
  int ebC   = ceil_div(E, CHUNK);

  // CSR build first (produces dis), then pre-scaled sliced feats
  bhistA_k<<<ebC, 256, 0, stream>>>(ei, bh, E, NB);
  bscan_k<<<1, 1024, 0, stream>>>(bh, bbase, NB);
  bpartC_k<<<ebC, 256, 0, stream>>>(ei, bbase, bcur, ebuf, E, NB);
  bbuildD_k<<<NB, 256, 0, stream>>>(ebuf, bh, bbase, rp, cnt, dis, csr, N);
  build_feats_k<<<nb256, 256, 0, stream>>>(x, semb, nemb, dis, feats, N);

  int TB = ceil_div(N, 128);         // node tiles (128 nodes per block)
  int gemmb = ceil_div(N, 64);

  // layer 1: sliced agg (4-slice grid, slice3 no-op) -> gemm18 (sliced+scaled out)
  aggsl_k<1><<<4 * TB, 256, 0, stream>>>(feats, dis, rp, cnt, csr, agg1, N, TB);
  gemm18_k<<<ceil_div(N, 8), 256, 0, stream>>>(agg1, W1, b1, dis, sl1, N);
  // layer 2: sliced agg (16 slices, 2 phases) -> gemm (sliced+scaled out)
  aggsl_k<0><<<16 * TB, 256, 0, stream>>>(sl1, dis, rp, cnt, csr, sl2, N, TB);
  gemm128_k<0><<<gemmb, 128, 0, stream>>>(sl2, W2, b2, dis, sl1, N);
  // layer 3: sliced agg -> gemm (row-major out, unscaled)
  aggsl_k<0><<<16 * TB, 256, 0, stream>>>(sl1, dis, rp, cnt, csr, sl2, N, TB);
  gemm128_k<1><<<gemmb, 128, 0, stream>>>(sl2, W3, b3, dis, sl1, N);  // sl1 now row-major h3

  // gap-node gather
  ghist_k<<<nb256, 256, 0, stream>>>(batch, gc, N);
  gscan_k<<<1, 1024, 0, stream>>>(gc, go, G);
  gather_k<<<G, H, 0, stream>>>(sl1, go, gap, ginp, ghf, ghb, G);

  // decoder: 3 steps
  int gb = ceil_div(G, 16);
  for (int t = 0; t < GAPLEN; ++t){
    gru_k<<<dim3(gb, 2), 256, 0, stream>>>(ginp, ghf, ghb,
                                           Wih_f, Whh_f, bih_f, bhh_f,
                                           Wih_b, Whh_b, bih_b, bhh_b, G);
    post_k<<<gb, 256, 0, stream>>>(ghf, ghb, Wred, bred, Wh1, bh1, Wh2, bh2,
                                   ginp, out, G, t);
  }
}